// Round 2
// baseline (404.974 us; speedup 1.0000x reference)
//
#include <hip/hip_runtime.h>
#include <math.h>

#define NUM_NODES 94
#define SEQ_LEN 784
#define OUT_CLASSES 10
#define EPB 32              // batch elements per block (2 groups of 16)
#define YP 104              // y LDS stride (f16): conflict-free b128 pattern
#define SP 396              // staged-input LDS stride (f32): 2-way (free), 16B-aligned
#define THALF 392           // input staged in two halves (LDS budget)

#define TWO_GAMMA 0.2f
#define OM2 0.0503551324598949f            // (2*pi/28)^2
#define INV_SQRT_N 0.103142124625879       // 1/sqrt(94)
#define LOG2E 1.4426950408889634
#define WSCALE ((float)(2.0 * INV_SQRT_N * LOG2E))

typedef _Float16 half8 __attribute__((ext_vector_type(8)));
typedef _Float16 half4 __attribute__((ext_vector_type(4)));
typedef float    floatx4 __attribute__((ext_vector_type(4)));
typedef float    f2 __attribute__((ext_vector_type(2)));

// 4 waves, 32 elements/block. Wave w: group g=w>>1 (elements 16g..16g+15),
// half tau=w&1 (rows 48tau..48tau+47 = 3 MFMA row-tiles). Each wave reads the
// y B-fragments ONCE for 48 output rows (vs once per 16 rows before): LDS read
// traffic per element drops 3x. Bias pre-added via MFMA C-operand chain.
__global__
__attribute__((amdgpu_flat_work_group_size(256, 256)))
void horn_kernel(
    const float* __restrict__ input,   // (1024, 784)
    const float* __restrict__ w_ih,    // (94, 1)
    const float* __restrict__ b_ih,    // (94)
    const float* __restrict__ w_hh,    // (94, 94)
    const float* __restrict__ b_hh,    // (94)
    const float* __restrict__ w_ro,    // (10, 94)
    const float* __restrict__ b_ro,    // (10)
    float* __restrict__ out)           // (1024, 10)
{
    __shared__ __align__(16) float    sinl[EPB * SP];        // 50,688 B (reused as xsh)
    __shared__ __align__(16) _Float16 ybuf[2][EPB * YP];     // 13,312 B   (total 64,000)

    const int tid  = threadIdx.x;
    const int w    = tid >> 6;         // wave 0..3
    const int lane = tid & 63;
    const int g    = w >> 1;           // element group
    const int tau  = w & 1;            // row half
    const int e    = lane & 15;        // MFMA col (element) / A row-within-tile
    const int h    = lane >> 4;        // 0..3 k-group / D row-group
    const int bb   = blockIdx.x;
    const int Eloc = 16 * g + e;       // element within block
    const int RB   = 48 * tau;         // this wave's row base

    // ---- zero both y buffers (y0 = 0) ----
    for (int i = tid; i < (2 * EPB * YP) / 2; i += 256) ((float*)ybuf)[i] = 0.0f;

    // ---- constants: A-frags (pre-scaled W), bias as MFMA C-init, w_ih ----
    half8 a[3][3];
    floatx4 biasC[3];
    f2 wih01[3], wih23[3];
    #pragma unroll
    for (int t3 = 0; t3 < 3; ++t3) {
        const int arow = RB + 16 * t3 + e;
        #pragma unroll
        for (int c = 0; c < 3; ++c) {
            #pragma unroll
            for (int i = 0; i < 8; ++i) {
                const int k = 32 * c + 8 * h + i;
                a[t3][c][i] = (_Float16)((arow < NUM_NODES && k < NUM_NODES)
                                ? w_hh[arow * NUM_NODES + k] * WSCALE : 0.0f);
            }
        }
        float bv[4], wv[4];
        #pragma unroll
        for (int r = 0; r < 4; ++r) {
            const int R = RB + 16 * t3 + 4 * h + r;
            bv[r] = (R < NUM_NODES) ? (b_ih[R] + b_hh[R]) * WSCALE : 0.0f;
            wv[r] = (R < NUM_NODES) ? w_ih[R] * WSCALE : 0.0f;
        }
        biasC[t3][0] = bv[0]; biasC[t3][1] = bv[1]; biasC[t3][2] = bv[2]; biasC[t3][3] = bv[3];
        wih01[t3][0] = wv[0]; wih01[t3][1] = wv[1];
        wih23[t3][0] = wv[2]; wih23[t3][1] = wv[3];
    }

    f2 x01[3], x23[3], y01[3], y23[3];
    #pragma unroll
    for (int t3 = 0; t3 < 3; ++t3) {
        x01[t3] = (f2){0.0f, 0.0f}; x23[t3] = (f2){0.0f, 0.0f};
        y01[t3] = (f2){0.0f, 0.0f}; y23[t3] = (f2){0.0f, 0.0f};
    }

    const int rb  = Eloc * YP + 8 * h;        // B-frag base (16B aligned, conflict-free)
    const int wb0 = Eloc * YP + RB + 4 * h;   // y publish base (+32B per tile)
    const int sb  = Eloc * SP;

    const f2 ng = {-TWO_GAMMA, -TWO_GAMMA};
    const f2 no = {-OM2, -OM2};

    #define HSTEP(RD, WR, T) do {                                                      \
        const _Float16* yr = &(RD)[rb];                                                \
        half8 B0 = *(const half8*)(yr);                                                \
        half8 B1 = *(const half8*)(yr + 32);                                           \
        half8 B2 = *(const half8*)(yr + 64);                                           \
        float st = sinl[sb + (T)];                                                     \
        f2 st2 = {st, st};                                                             \
        _Float16* yw = &(WR)[wb0];                                                     \
        _Pragma("unroll")                                                              \
        for (int t3 = 0; t3 < 3; ++t3) {                                               \
            floatx4 d = biasC[t3];                                                     \
            d = __builtin_amdgcn_mfma_f32_16x16x32_f16(a[t3][0], B0, d, 0, 0, 0);      \
            d = __builtin_amdgcn_mfma_f32_16x16x32_f16(a[t3][1], B1, d, 0, 0, 0);      \
            d = __builtin_amdgcn_mfma_f32_16x16x32_f16(a[t3][2], B2, d, 0, 0, 0);      \
            f2 S01 = {d[0], d[1]}, S23 = {d[2], d[3]};                                 \
            f2 e01 = st2 * wih01[t3] + S01;                                            \
            f2 e23 = st2 * wih23[t3] + S23;                                            \
            f2 t01, t23;                                                               \
            t01[0] = 0.5f - __builtin_amdgcn_rcpf(__builtin_amdgcn_exp2f(e01[0]) + 1.0f); \
            t01[1] = 0.5f - __builtin_amdgcn_rcpf(__builtin_amdgcn_exp2f(e01[1]) + 1.0f); \
            t23[0] = 0.5f - __builtin_amdgcn_rcpf(__builtin_amdgcn_exp2f(e23[0]) + 1.0f); \
            t23[1] = 0.5f - __builtin_amdgcn_rcpf(__builtin_amdgcn_exp2f(e23[1]) + 1.0f); \
            t01 = ng * y01[t3] + t01;  t01 = no * x01[t3] + t01;                       \
            t23 = ng * y23[t3] + t23;  t23 = no * x23[t3] + t23;                       \
            x01[t3] += y01[t3];  x23[t3] += y23[t3];                                   \
            y01[t3] += t01;      y23[t3] += t23;                                       \
            half4 yh;                                                                  \
            yh[0] = (_Float16)y01[t3][0]; yh[1] = (_Float16)y01[t3][1];                \
            yh[2] = (_Float16)y23[t3][0]; yh[3] = (_Float16)y23[t3][1];                \
            *(half4*)(yw + 16 * t3) = yh;                                              \
        }                                                                              \
        __syncthreads();                                                               \
    } while (0)

    for (int hf = 0; hf < 2; ++hf) {
        __syncthreads();
        // ---- stage this half of the input rows (f32, float4-coalesced) ----
        {
            const float* src = input + (size_t)bb * EPB * SEQ_LEN + hf * THALF;
            for (int idx = tid; idx < EPB * (THALF / 4); idx += 256) {
                int ee = idx / (THALF / 4);
                int cc = idx - ee * (THALF / 4);
                *(floatx4*)&sinl[ee * SP + 4 * cc] =
                    *(const floatx4*)(src + (size_t)ee * SEQ_LEN + 4 * cc);
            }
        }
        __syncthreads();
        for (int t = 0; t < THALF; t += 2) {
            HSTEP(ybuf[0], ybuf[1], t);
            HSTEP(ybuf[1], ybuf[0], t + 1);
        }
    }
    #undef HSTEP

    // ---- epilogue: gather x (f32, reuse sinl), project to classes ----
    float* xsh = sinl;   // last HSTEP ended with __syncthreads
    #pragma unroll
    for (int t3 = 0; t3 < 3; ++t3) {
        floatx4 xv;
        xv[0] = x01[t3][0]; xv[1] = x01[t3][1]; xv[2] = x23[t3][0]; xv[3] = x23[t3][1];
        *(floatx4*)&xsh[Eloc * YP + RB + 16 * t3 + 4 * h] = xv;
    }
    __syncthreads();

    for (int idx = tid; idx < EPB * OUT_CLASSES; idx += 256) {
        const int ee = idx / OUT_CLASSES;
        const int c  = idx - ee * OUT_CLASSES;
        float acc = b_ro[c];
        #pragma unroll 2
        for (int r = 0; r < NUM_NODES; ++r)
            acc += xsh[ee * YP + r] * w_ro[c * NUM_NODES + r];
        out[((size_t)bb * EPB + ee) * OUT_CLASSES + c] = acc;
    }
}

extern "C" void kernel_launch(void* const* d_in, const int* in_sizes, int n_in,
                              void* d_out, int out_size, void* d_ws, size_t ws_size,
                              hipStream_t stream) {
    const float* input = (const float*)d_in[0];
    const float* w_ih  = (const float*)d_in[1];
    const float* b_ih  = (const float*)d_in[2];
    const float* w_hh  = (const float*)d_in[3];
    const float* b_hh  = (const float*)d_in[4];
    const float* w_ro  = (const float*)d_in[5];
    const float* b_ro  = (const float*)d_in[6];
    float* out = (float*)d_out;

    const int batch = in_sizes[0] / SEQ_LEN;   // 1024
    dim3 grid(batch / EPB);                    // 32 blocks of 32 elements
    dim3 block(256);                           // 4 waves

    hipLaunchKernelGGL(horn_kernel, grid, block, 0, stream,
                       input, w_ih, b_ih, w_hh, b_hh, w_ro, b_ro, out);
}

// Round 3
// 332.753 us; speedup vs baseline: 1.2170x; 1.2170x over previous
//
#include <hip/hip_runtime.h>
#include <math.h>

#define NUM_NODES 94
#define SEQ_LEN 784
#define OUT_CLASSES 10
#define EPB 16              // batch elements per block (MFMA N dim)
#define NW 4                // waves per block: 1 wave per SIMD, zero issue contention
#define YP 104              // y LDS stride (f16): 13 16B-slots/row -> conflict-free b128
#define SP 788              // input LDS stride (f32), 16B-aligned, 2-way max

#define TWO_GAMMA 0.2f
#define OM2 0.0503551324598949f            // (2*pi/28)^2
#define INV_SQRT_N 0.103142124625879       // 1/sqrt(94)
#define LOG2E 1.4426950408889634
#define WSCALE ((float)(2.0 * INV_SQRT_N * LOG2E))

typedef _Float16 half8 __attribute__((ext_vector_type(8)));
typedef _Float16 half4 __attribute__((ext_vector_type(4)));
typedef float    floatx4 __attribute__((ext_vector_type(4)));
typedef float    f2 __attribute__((ext_vector_type(2)));

// R3: 4 waves (1/SIMD), EPB=16, tiles 2/2/1/1.
// Wave 0: tiles {0,1}; wave 1: {2,3}; wave 2: {4}; wave 3: {5}.
// Per step per wave: 3x ds_read_b128 (full y), 3 or 6 MFMA (2 parallel chains
// of depth 2 per tile), dynamics for owned rows only, publish owned rows.
// Input scalar for step t+1 prefetched before the barrier.
__global__
__attribute__((amdgpu_flat_work_group_size(NW*64, NW*64)))
void horn_kernel(
    const float* __restrict__ input,   // (1024, 784)
    const float* __restrict__ w_ih,    // (94, 1)
    const float* __restrict__ b_ih,    // (94)
    const float* __restrict__ w_hh,    // (94, 94)
    const float* __restrict__ b_hh,    // (94)
    const float* __restrict__ w_ro,    // (10, 94)
    const float* __restrict__ b_ro,    // (10)
    float* __restrict__ out)           // (1024, 10)
{
    __shared__ __align__(16) float    sinl[EPB * SP];        // 50,432 B (reused as xsh)
    __shared__ __align__(16) _Float16 ybuf[2][EPB * YP];     //  6,656 B  (total 57,088)

    const int tid  = threadIdx.x;
    const int w    = tid >> 6;         // wave 0..3
    const int lane = tid & 63;
    const int e    = lane & 15;        // element (B/D col); A row-within-tile
    const int h    = lane >> 4;        // 0..3 (k-group / D row-group)
    const int bb   = blockIdx.x;

    const int  TA  = (w < 2) ? 2 * w : (w + 2);   // first owned tile
    const int  TB  = 2 * w + 1;                   // second owned tile (w<2 only)
    const bool two = (w < 2);

    // ---- stage input rows to LDS (f32, float4-coalesced) ----
    {
        const floatx4* in4 = (const floatx4*)(input + (size_t)bb * EPB * SEQ_LEN);
        for (int idx = tid; idx < EPB * (SEQ_LEN / 4); idx += NW * 64) {
            int ee = idx / (SEQ_LEN / 4);
            int cc = idx - ee * (SEQ_LEN / 4);
            *(floatx4*)&sinl[ee * SP + 4 * cc] = in4[ee * (SEQ_LEN / 4) + cc];
        }
    }
    // ---- zero both y buffers (y0 = 0) ----
    for (int i = tid; i < (2 * EPB * YP) / 2; i += NW * 64) ((float*)ybuf)[i] = 0.0f;

    // ---- constants per owned tile: A-frags, bias (as MFMA C-init), w_ih ----
    #define LOAD_TILE(T, A0, A1, A2, BIASC, WIH01, WIH23) do {                     \
        const int arow = 16 * (T) + e;                                             \
        _Pragma("unroll")                                                          \
        for (int i = 0; i < 8; ++i) {                                              \
            const int k = 8 * h + i;                                               \
            (A0)[i] = (_Float16)((arow < NUM_NODES && k      < NUM_NODES)          \
                        ? w_hh[arow * NUM_NODES + k     ] * WSCALE : 0.0f);        \
            (A1)[i] = (_Float16)((arow < NUM_NODES && k + 32 < NUM_NODES)          \
                        ? w_hh[arow * NUM_NODES + k + 32] * WSCALE : 0.0f);        \
            (A2)[i] = (_Float16)((arow < NUM_NODES && k + 64 < NUM_NODES)          \
                        ? w_hh[arow * NUM_NODES + k + 64] * WSCALE : 0.0f);        \
        }                                                                          \
        _Pragma("unroll")                                                          \
        for (int r = 0; r < 4; ++r) {                                              \
            const int R = 16 * (T) + 4 * h + r;                                    \
            const float bv = (R < NUM_NODES) ? (b_ih[R] + b_hh[R]) * WSCALE : 0.0f;\
            const float wv = (R < NUM_NODES) ? w_ih[R] * WSCALE : 0.0f;            \
            (BIASC)[r] = bv;                                                       \
            if (r < 2) (WIH01)[r] = wv; else (WIH23)[r - 2] = wv;                   \
        }                                                                          \
    } while (0)

    half8 aA0, aA1, aA2, aB0, aB1, aB2;
    floatx4 biasA = {0,0,0,0}, biasB = {0,0,0,0};
    f2 wihA01 = {0,0}, wihA23 = {0,0}, wihB01 = {0,0}, wihB23 = {0,0};
    LOAD_TILE(TA, aA0, aA1, aA2, biasA, wihA01, wihA23);
    if (two) { LOAD_TILE(TB, aB0, aB1, aB2, biasB, wihB01, wihB23); }
    #undef LOAD_TILE

    f2 xA01 = {0,0}, xA23 = {0,0}, yA01 = {0,0}, yA23 = {0,0};
    f2 xB01 = {0,0}, xB23 = {0,0}, yB01 = {0,0}, yB23 = {0,0};

    const int rb  = e * YP + 8 * h;            // B-frag base (conflict-free b128)
    const int wbA = e * YP + 16 * TA + 4 * h;  // publish base, tile A
    const int wbB = e * YP + 16 * TB + 4 * h;  // publish base, tile B
    const int sb  = e * SP;

    const floatx4 zf4 = {0,0,0,0};
    const f2 ng = {-TWO_GAMMA, -TWO_GAMMA};
    const f2 no = {-OM2, -OM2};

    __syncthreads();   // staging + y-init visible

    float st = sinl[sb];   // step-0 input

    // Dynamics for one owned tile from its D vector (bias already inside d).
    #define DYN(d, WIH01, WIH23, X01, X23, Y01, Y23, WR, WOFF) do {                \
        f2 st2 = { st, st };                                                       \
        f2 e01 = st2 * (WIH01) + (f2){ (d)[0], (d)[1] };                           \
        f2 e23 = st2 * (WIH23) + (f2){ (d)[2], (d)[3] };                           \
        f2 t01, t23;                                                               \
        t01[0] = 0.5f - __builtin_amdgcn_rcpf(__builtin_amdgcn_exp2f(e01[0]) + 1.0f); \
        t01[1] = 0.5f - __builtin_amdgcn_rcpf(__builtin_amdgcn_exp2f(e01[1]) + 1.0f); \
        t23[0] = 0.5f - __builtin_amdgcn_rcpf(__builtin_amdgcn_exp2f(e23[0]) + 1.0f); \
        t23[1] = 0.5f - __builtin_amdgcn_rcpf(__builtin_amdgcn_exp2f(e23[1]) + 1.0f); \
        t01 = ng * (Y01) + t01;  t01 = no * (X01) + t01;                           \
        t23 = ng * (Y23) + t23;  t23 = no * (X23) + t23;                           \
        (X01) += (Y01);  (X23) += (Y23);                                           \
        (Y01) += t01;    (Y23) += t23;                                             \
        half4 yh;                                                                  \
        yh[0] = (_Float16)(Y01)[0]; yh[1] = (_Float16)(Y01)[1];                    \
        yh[2] = (_Float16)(Y23)[0]; yh[3] = (_Float16)(Y23)[1];                    \
        *(half4*)&(WR)[WOFF] = yh;                                                 \
    } while (0)

    #define HSTEP(RD, WR, T) do {                                                  \
        const _Float16* yr = &(RD)[rb];                                            \
        half8 B0 = *(const half8*)(yr);                                            \
        half8 B1 = *(const half8*)(yr + 32);                                       \
        half8 B2 = *(const half8*)(yr + 64);                                       \
        const int tn = ((T) + 1 < SEQ_LEN) ? (T) + 1 : (SEQ_LEN - 1);              \
        float stn = sinl[sb + tn];                                                 \
        /* tile A: two parallel MFMA chains (depth 2) + combine */                 \
        floatx4 dA  = __builtin_amdgcn_mfma_f32_16x16x32_f16(aA0, B0, biasA, 0, 0, 0); \
        floatx4 dA2 = __builtin_amdgcn_mfma_f32_16x16x32_f16(aA1, B1, zf4,  0, 0, 0); \
        dA = __builtin_amdgcn_mfma_f32_16x16x32_f16(aA2, B2, dA, 0, 0, 0);         \
        if (two) {                                                                 \
            floatx4 dB  = __builtin_amdgcn_mfma_f32_16x16x32_f16(aB0, B0, biasB, 0, 0, 0); \
            floatx4 dB2 = __builtin_amdgcn_mfma_f32_16x16x32_f16(aB1, B1, zf4,  0, 0, 0); \
            dB = __builtin_amdgcn_mfma_f32_16x16x32_f16(aB2, B2, dB, 0, 0, 0);     \
            dB += dB2;                                                             \
            dA += dA2;                                                             \
            DYN(dA, wihA01, wihA23, xA01, xA23, yA01, yA23, WR, wbA);              \
            DYN(dB, wihB01, wihB23, xB01, xB23, yB01, yB23, WR, wbB);              \
        } else {                                                                   \
            dA += dA2;                                                             \
            DYN(dA, wihA01, wihA23, xA01, xA23, yA01, yA23, WR, wbA);              \
        }                                                                          \
        st = stn;                                                                  \
        __syncthreads();                                                           \
    } while (0)

    for (int t = 0; t < SEQ_LEN; t += 2) {
        HSTEP(ybuf[0], ybuf[1], t);
        HSTEP(ybuf[1], ybuf[0], t + 1);
    }
    #undef HSTEP
    #undef DYN

    // ---- epilogue: gather x (f32, reuse sinl), project to classes ----
    float* xsh = sinl;   // last HSTEP ended with __syncthreads
    {
        floatx4 xv;
        xv[0] = xA01[0]; xv[1] = xA01[1]; xv[2] = xA23[0]; xv[3] = xA23[1];
        *(floatx4*)&xsh[e * YP + 16 * TA + 4 * h] = xv;
        if (two) {
            floatx4 xw;
            xw[0] = xB01[0]; xw[1] = xB01[1]; xw[2] = xB23[0]; xw[3] = xB23[1];
            *(floatx4*)&xsh[e * YP + 16 * TB + 4 * h] = xw;
        }
    }
    __syncthreads();

    for (int idx = tid; idx < EPB * OUT_CLASSES; idx += NW * 64) {
        const int ee = idx / OUT_CLASSES;
        const int c  = idx - ee * OUT_CLASSES;
        float acc = b_ro[c];
        #pragma unroll 2
        for (int r = 0; r < NUM_NODES; ++r)
            acc += xsh[ee * YP + r] * w_ro[c * NUM_NODES + r];
        out[((size_t)bb * EPB + ee) * OUT_CLASSES + c] = acc;
    }
}

extern "C" void kernel_launch(void* const* d_in, const int* in_sizes, int n_in,
                              void* d_out, int out_size, void* d_ws, size_t ws_size,
                              hipStream_t stream) {
    const float* input = (const float*)d_in[0];
    const float* w_ih  = (const float*)d_in[1];
    const float* b_ih  = (const float*)d_in[2];
    const float* w_hh  = (const float*)d_in[3];
    const float* b_hh  = (const float*)d_in[4];
    const float* w_ro  = (const float*)d_in[5];
    const float* b_ro  = (const float*)d_in[6];
    float* out = (float*)d_out;

    const int batch = in_sizes[0] / SEQ_LEN;   // 1024
    dim3 grid(batch / EPB);                    // 64 blocks of 16 elements
    dim3 block(NW * 64);                       // 4 waves, 1 per SIMD

    hipLaunchKernelGGL(horn_kernel, grid, block, 0, stream,
                       input, w_ih, b_ih, w_hh, b_hh, w_ro, b_ro, out);
}

// Round 4
// 303.411 us; speedup vs baseline: 1.3347x; 1.0967x over previous
//
#include <hip/hip_runtime.h>
#include <math.h>

#define NUM_NODES 94
#define SEQ_LEN 784
#define OUT_CLASSES 10
#define EPB 16              // batch elements per block (MFMA N dim)
#define NW 6                // waves: 1 tile (16 rows) each; tiles 0..5 cover 96 rows
#define SP 788              // staged-input LDS stride (f32): 2-way max (free)
#define YHALF 1664          // f16 units per y buffer (max eoff 1564 + 96)

#define TWO_GAMMA 0.2f
#define OM2 0.0503551324598949f            // (2*pi/28)^2
#define INV_SQRT_N 0.103142124625879       // 1/sqrt(94)
#define LOG2E 1.4426950408889634
// exp2 arg = 2A*log2e -> fold 2*INV_SQRT_N*LOG2E into W, w_ih, bias (K-slots)
#define WSCALE ((float)(2.0 * INV_SQRT_N * LOG2E))

typedef _Float16 half8 __attribute__((ext_vector_type(8)));
typedef _Float16 half4 __attribute__((ext_vector_type(4)));
typedef _Float16 half2v __attribute__((ext_vector_type(2)));
typedef float    floatx4 __attribute__((ext_vector_type(4)));
typedef float    f2 __attribute__((ext_vector_type(2)));

// R4: 6 waves x 1 tile (measured-best frame) + input/bias folded into K
// (rows 94=s_t, 95=1.0) + skewed y layout (zero bank conflicts on reads AND
// publishes) + deferred-leak precompute (u = 0.8y - w2*x + 0.5 during read
// stall; post-MFMA tail = exp2,+1,rcp,sub,cvt,write only).
// y layout: element e base (f16 units) = 104e + 4*(e>>3); row r at base + r.
__global__
__attribute__((amdgpu_flat_work_group_size(NW*64, NW*64)))
void horn_kernel(
    const float* __restrict__ input,   // (1024, 784)
    const float* __restrict__ w_ih,    // (94, 1)
    const float* __restrict__ b_ih,    // (94)
    const float* __restrict__ w_hh,    // (94, 94)
    const float* __restrict__ b_hh,    // (94)
    const float* __restrict__ w_ro,    // (10, 94)
    const float* __restrict__ b_ro,    // (10)
    float* __restrict__ out)           // (1024, 10)
{
    __shared__ __align__(16) float    sinl[EPB * SP];     // 50,432 B (reused as xsh)
    __shared__ __align__(16) _Float16 ybuf[2][YHALF];     //  6,656 B (total 57,088)

    const int tid  = threadIdx.x;
    const int w    = tid >> 6;         // wave = tile id 0..5
    const int lane = tid & 63;
    const int e    = lane & 15;        // element (B/D col); A row-within-tile
    const int h    = lane >> 4;        // 0..3 (k-group / D row-group)
    const int bb   = blockIdx.x;

    const int  T        = w;                      // owned 16-row tile
    const bool duty     = (w == 3 && h == 0);     // writes s_{t+1} -> row 94
    const bool tailmask = (w == 5 && h == 3);     // rows 92,93 only (94,95 = input slots)

    const int eoff = 104 * e + 4 * (e >> 3);      // skewed element base (f16 units)

    // ---- stage input rows to LDS (f32, float4-coalesced) ----
    {
        const floatx4* in4 = (const floatx4*)(input + (size_t)bb * EPB * SEQ_LEN);
        for (int idx = tid; idx < EPB * (SEQ_LEN / 4); idx += NW * 64) {
            int ee = idx / (SEQ_LEN / 4);
            int cc = idx - ee * (SEQ_LEN / 4);
            *(floatx4*)&sinl[ee * SP + 4 * cc] = in4[ee * (SEQ_LEN / 4) + cc];
        }
    }
    // ---- zero both y buffers ----
    for (int i = tid; i < (2 * YHALF) / 2; i += NW * 64) ((float*)ybuf)[i] = 0.0f;

    // ---- A fragments: W rows 16T+e, cols k; cols 94/95 = w_ih, bias ----
    const int arow = 16 * T + e;
    half8 a0, a1, a2;
    #pragma unroll
    for (int i = 0; i < 8; ++i) {
        const int k = 8 * h + i;
        float v0 = 0.0f, v1 = 0.0f, v2 = 0.0f;
        if (arow < NUM_NODES) {
            v0 = w_hh[arow * NUM_NODES + k] * WSCALE;
            if (k + 32 < NUM_NODES) v1 = w_hh[arow * NUM_NODES + k + 32] * WSCALE;
            const int k2 = k + 64;
            if      (k2 <  NUM_NODES) v2 = w_hh[arow * NUM_NODES + k2] * WSCALE;
            else if (k2 == NUM_NODES) v2 = w_ih[arow] * WSCALE;                  // s_t slot
            else                      v2 = (b_ih[arow] + b_hh[arow]) * WSCALE;   // 1.0 slot
        }
        a0[i] = (_Float16)v0; a1[i] = (_Float16)v1; a2[i] = (_Float16)v2;
    }

    f2 x01 = {0,0}, x23 = {0,0}, y01 = {0,0}, y23 = {0,0};

    const floatx4 zf4 = {0,0,0,0};
    const f2 no2 = {-OM2, -OM2};
    const f2 p82 = {1.0f - TWO_GAMMA, 1.0f - TWO_GAMMA};   // 0.8
    const f2 h05 = {0.5f, 0.5f};

    __syncthreads();   // staging + zero visible

    // ---- seed input slots: row 94 = s_0 (buf0), row 95 = 1.0 (both) ----
    if (tid < EPB) {
        const int eo = 104 * tid + 4 * (tid >> 3);
        const float s0 = input[((size_t)bb * EPB + tid) * SEQ_LEN];
        half2v v0; v0[0] = (_Float16)s0; v0[1] = (_Float16)1.0f;
        half2v v1; v1[0] = (_Float16)0.0f; v1[1] = (_Float16)1.0f;
        *(half2v*)&ybuf[0][eo + NUM_NODES] = v0;
        *(half2v*)&ybuf[1][eo + NUM_NODES] = v1;
    }
    __syncthreads();

    #define HSTEP(RP, WP, T_) do {                                                 \
        const _Float16* Yb = &ybuf[RP][eoff + 8 * h];                              \
        half4 l0 = *(const half4*)(Yb);                                            \
        half4 u0 = *(const half4*)(Yb + 4);                                        \
        half4 l1 = *(const half4*)(Yb + 32);                                       \
        half4 u1 = *(const half4*)(Yb + 36);                                       \
        half4 l2 = *(const half4*)(Yb + 64);                                       \
        half4 u2 = *(const half4*)(Yb + 68);                                       \
        /* deferred-leak precompute fills the read stall */                        \
        f2 q01 = no2 * x01 + h05;  q01 = p82 * y01 + q01;                          \
        f2 q23 = no2 * x23 + h05;  q23 = p82 * y23 + q23;                          \
        x01 += y01;  x23 += y23;                                                   \
        float snext = 0.0f;                                                        \
        if (duty) {                                                                \
            const int tn = ((T_) + 1 < SEQ_LEN) ? (T_) + 1 : (SEQ_LEN - 1);        \
            snext = sinl[e * SP + tn];                                             \
        }                                                                          \
        half8 B0 = __builtin_shufflevector(l0, u0, 0, 1, 2, 3, 4, 5, 6, 7);        \
        half8 B1 = __builtin_shufflevector(l1, u1, 0, 1, 2, 3, 4, 5, 6, 7);        \
        half8 B2 = __builtin_shufflevector(l2, u2, 0, 1, 2, 3, 4, 5, 6, 7);        \
        floatx4 d0 = __builtin_amdgcn_mfma_f32_16x16x32_f16(a0, B0, zf4, 0, 0, 0); \
        floatx4 d1 = __builtin_amdgcn_mfma_f32_16x16x32_f16(a1, B1, zf4, 0, 0, 0); \
        floatx4 d2 = __builtin_amdgcn_mfma_f32_16x16x32_f16(a2, B2, zf4, 0, 0, 0); \
        floatx4 d = (d0 + d1) + d2;   /* d = full exp2 argument (bias+input in) */ \
        f2 r01, r23;                                                               \
        r01[0] = __builtin_amdgcn_rcpf(__builtin_amdgcn_exp2f(d[0]) + 1.0f);       \
        r01[1] = __builtin_amdgcn_rcpf(__builtin_amdgcn_exp2f(d[1]) + 1.0f);       \
        r23[0] = __builtin_amdgcn_rcpf(__builtin_amdgcn_exp2f(d[2]) + 1.0f);       \
        r23[1] = __builtin_amdgcn_rcpf(__builtin_amdgcn_exp2f(d[3]) + 1.0f);       \
        y01 = q01 - r01;  y23 = q23 - r23;                                         \
        half4 yh;                                                                  \
        yh[0] = (_Float16)y01[0]; yh[1] = (_Float16)y01[1];                        \
        yh[2] = (_Float16)y23[0]; yh[3] = (_Float16)y23[1];                        \
        if (tailmask) {                                                            \
            half2v yt; yt[0] = yh[0]; yt[1] = yh[1];   /* rows 92,93 only */       \
            *(half2v*)&ybuf[WP][eoff + 92] = yt;                                   \
        } else {                                                                   \
            *(half4*)&ybuf[WP][eoff + 16 * T + 4 * h] = yh;                        \
        }                                                                          \
        if (duty) {                                                                \
            half2v sv; sv[0] = (_Float16)snext; sv[1] = (_Float16)1.0f;            \
            *(half2v*)&ybuf[WP][eoff + NUM_NODES] = sv;                            \
        }                                                                          \
        __syncthreads();                                                           \
    } while (0)

    for (int t = 0; t < SEQ_LEN; t += 2) {
        HSTEP(0, 1, t);
        HSTEP(1, 0, t + 1);
    }
    #undef HSTEP

    // ---- epilogue: gather x (f32, overlay on sinl), project to classes ----
    float* xsh = sinl;   // last HSTEP ended with __syncthreads
    {
        floatx4 xv;
        xv[0] = x01[0]; xv[1] = x01[1]; xv[2] = x23[0]; xv[3] = x23[1];
        *(floatx4*)&xsh[e * 104 + 16 * T + 4 * h] = xv;
    }
    __syncthreads();

    if (tid < EPB * OUT_CLASSES) {
        const int ee = tid / OUT_CLASSES;
        const int c  = tid - ee * OUT_CLASSES;
        float acc = b_ro[c];
        #pragma unroll 2
        for (int r = 0; r < NUM_NODES; ++r)
            acc += xsh[ee * 104 + r] * w_ro[c * NUM_NODES + r];
        out[((size_t)bb * EPB + ee) * OUT_CLASSES + c] = acc;
    }
}

extern "C" void kernel_launch(void* const* d_in, const int* in_sizes, int n_in,
                              void* d_out, int out_size, void* d_ws, size_t ws_size,
                              hipStream_t stream) {
    const float* input = (const float*)d_in[0];
    const float* w_ih  = (const float*)d_in[1];
    const float* b_ih  = (const float*)d_in[2];
    const float* w_hh  = (const float*)d_in[3];
    const float* b_hh  = (const float*)d_in[4];
    const float* w_ro  = (const float*)d_in[5];
    const float* b_ro  = (const float*)d_in[6];
    float* out = (float*)d_out;

    const int batch = in_sizes[0] / SEQ_LEN;   // 1024
    dim3 grid(batch / EPB);                    // 64 blocks of 16 elements
    dim3 block(NW * 64);                       // 6 waves

    hipLaunchKernelGGL(horn_kernel, grid, block, 0, stream,
                       input, w_ih, b_ih, w_hh, b_hh, w_ro, b_ro, out);
}